// Round 3
// baseline (52.535 us; speedup 1.0000x reference)
//
#include <hip/hip_runtime.h>
#include <hip/hip_cooperative_groups.h>

namespace cg = cooperative_groups;

#define EPS 1e-6f

__global__ __launch_bounds__(256) void iou_coop_kernel(
    const float2* __restrict__ pred4,  // layer-4 base, (B=16, N=4096) float2
    const float2* __restrict__ gt4,    // layer-4 base, (B=16, T=96) float2
    const int* __restrict__ bs_ptr,
    float* __restrict__ out,
    float* __restrict__ partial)       // [256] in d_ws
{
    __shared__ float2 gts[96];
    __shared__ float wave_part[4];

    const int tid = threadIdx.x;
    const int blk = blockIdx.x;
    const int b  = blk >> 4;   // 16 n-chunks per b
    const int nc = blk & 15;

    if (tid < 96) gts[tid] = gt4[b * 96 + tid];
    __syncthreads();

    const float2 p = pred4[b * 4096 + nc * 256 + tid];
    const float s = p.x, e = p.y;

    float acc = 0.0f;  // sum of log2(iou) over valid pairs
#pragma unroll 8
    for (int t = 0; t < 96; ++t) {
        const float a  = gts[t].x;
        const float bb = gts[t].y;
        const bool c0 = (s < a) & (e > bb);
        const bool c1 = (s < a) & (e < bb) & (e > a);
        const bool c2 = (s > a) & (s < bb) & (e > bb);
        const float num = c0 ? (bb - a) : (c1 ? (e - a) : (bb - s));
        const float den = c0 ? (e - s)  : (c1 ? (bb - s) : (e - a));
        // conditions mutually exclusive; den > 0 whenever any holds.
        // iou < EPS (incl. no-overlap / pred-inside-gt / num==0) -> ref maps to 1.0 -> log 0.
        const bool valid = (c0 | c1 | c2) && (num >= EPS * den);
        const float contrib = __log2f(num) - __log2f(den);
        acc += valid ? contrib : 0.0f;   // cndmask: NaN from garbage logs never selected
    }

    // block reduce: wave butterfly then LDS across the 4 waves
    for (int off = 32; off; off >>= 1)
        acc += __shfl_down(acc, off);
    if ((tid & 63) == 0) wave_part[tid >> 6] = acc;
    __syncthreads();
    if (tid == 0)
        partial[blk] = wave_part[0] + wave_part[1] + wave_part[2] + wave_part[3];

    cg::this_grid().sync();

    if (blk == 0) {
        float v = partial[tid];
        for (int off = 32; off; off >>= 1)
            v += __shfl_down(v, off);
        if ((tid & 63) == 0) wave_part[tid >> 6] = v;
        __syncthreads();
        if (tid == 0) {
            const float total = wave_part[0] + wave_part[1] + wave_part[2] + wave_part[3];
            // loss = -sum(ln(iou)) / batch = -ln2 * sum(log2(iou)) / batch
            out[0] = total * (-0.69314718055994531f / (float)bs_ptr[0]);
        }
    }
}

extern "C" void kernel_launch(void* const* d_in, const int* in_sizes, int n_in,
                              void* d_out, int out_size, void* d_ws, size_t ws_size,
                              hipStream_t stream) {
    (void)in_sizes; (void)n_in; (void)ws_size; (void)out_size;

    const float* pred = (const float*)d_in[0];   // (L,B,N,2) f32
    const float* gt   = (const float*)d_in[1];   // (L,B,T,2) f32
    const int*   bs   = (const int*)d_in[2];     // scalar
    float*       out  = (float*)d_out;
    float*       partial = (float*)d_ws;         // 256 floats

    const int L = 5, B = 16, N = 4096, T = 96;
    const float2* pred4 = (const float2*)pred + (size_t)(L - 1) * B * N;  // layer L-1
    const float2* gt4   = (const float2*)gt   + (size_t)(L - 1) * B * T;

    void* args[] = {(void*)&pred4, (void*)&gt4, (void*)&bs, (void*)&out, (void*)&partial};
    hipLaunchCooperativeKernel((const void*)iou_coop_kernel,
                               dim3(B * 16), dim3(256), args, 0, stream);
}

// Round 4
// 24.541 us; speedup vs baseline: 2.1407x; 2.1407x over previous
//
#include <hip/hip_runtime.h>

#define EPS 1e-6f
#define MAGIC 0x5A5A5A5Aull   // != 0xAAAAAAAA poison, != 0 reset

__global__ __launch_bounds__(256) void iou_onepass_kernel(
    const float2* __restrict__ pred4,  // layer-4 base, (B=16, N=4096) float2
    const float2* __restrict__ gt4,    // layer-4 base, (B=16, T=96) float2
    const int* __restrict__ bs_ptr,
    float* __restrict__ out,
    unsigned long long* __restrict__ slots)  // [256] in d_ws
{
    __shared__ float2 gts[96];
    __shared__ float wave_part[4];

    const int tid = threadIdx.x;
    const int blk = blockIdx.x;
    const int b  = blk >> 4;   // 16 n-chunks per b
    const int nc = blk & 15;

    if (tid < 96) gts[tid] = gt4[b * 96 + tid];
    __syncthreads();

    const float2 p = pred4[b * 4096 + nc * 256 + tid];
    const float s = p.x, e = p.y;

    float acc = 0.0f;  // sum of log2(iou) over valid pairs
#pragma unroll 8
    for (int t = 0; t < 96; ++t) {
        const float a  = gts[t].x;
        const float bb = gts[t].y;
        const bool c0 = (s < a) & (e > bb);
        const bool c1 = (s < a) & (e < bb) & (e > a);
        const bool c2 = (s > a) & (s < bb) & (e > bb);
        const float num = c0 ? (bb - a) : (c1 ? (e - a) : (bb - s));
        const float den = c0 ? (e - s)  : (c1 ? (bb - s) : (e - a));
        // conditions mutually exclusive; den > 0 whenever any holds.
        // iou < EPS (incl. no-overlap / pred-inside-gt) -> ref maps to 1.0 -> log 0.
        const bool valid = (c0 | c1 | c2) && (num >= EPS * den);
        const float contrib = __log2f(num) - __log2f(den);
        acc += valid ? contrib : 0.0f;   // cndmask: NaN from garbage logs never selected
    }

    // block reduce: wave butterfly then LDS across the 4 waves
    for (int off = 32; off; off >>= 1)
        acc += __shfl_down(acc, off);
    if ((tid & 63) == 0) wave_part[tid >> 6] = acc;
    __syncthreads();

    // publish {MAGIC | partial} as one 64-bit agent-scope word; producers exit.
    if (tid == 0) {
        const float part = wave_part[0] + wave_part[1] + wave_part[2] + wave_part[3];
        const unsigned long long word =
            (MAGIC << 32) | (unsigned long long)__float_as_uint(part);
        __hip_atomic_store(&slots[blk], word, __ATOMIC_RELEASE, __HIP_MEMORY_SCOPE_AGENT);
    }
    if (blk != 0) return;

    __syncthreads();  // wave_part phase-1 reads done before phase-2 writes

    // block 0: thread tid polls slot tid until this replay's publish lands.
    unsigned long long v;
    do {
        v = __hip_atomic_load(&slots[tid], __ATOMIC_RELAXED, __HIP_MEMORY_SCOPE_AGENT);
    } while ((v >> 32) != MAGIC);
    float part = __uint_as_float((unsigned int)v);
    // reset slot so the next replay re-waits (no cross-replay state reliance)
    __hip_atomic_store(&slots[tid], 0ull, __ATOMIC_RELAXED, __HIP_MEMORY_SCOPE_AGENT);

    for (int off = 32; off; off >>= 1)
        part += __shfl_down(part, off);
    if ((tid & 63) == 0) wave_part[tid >> 6] = part;
    __syncthreads();

    if (tid == 0) {
        const float total = wave_part[0] + wave_part[1] + wave_part[2] + wave_part[3];
        // loss = -sum(ln(iou)) / batch = -ln2 * sum(log2(iou)) / batch
        out[0] = total * (-0.69314718055994531f / (float)bs_ptr[0]);
    }
}

extern "C" void kernel_launch(void* const* d_in, const int* in_sizes, int n_in,
                              void* d_out, int out_size, void* d_ws, size_t ws_size,
                              hipStream_t stream) {
    (void)in_sizes; (void)n_in; (void)ws_size; (void)out_size;

    const float* pred = (const float*)d_in[0];   // (L,B,N,2) f32
    const float* gt   = (const float*)d_in[1];   // (L,B,T,2) f32
    const int*   bs   = (const int*)d_in[2];     // scalar
    float*       out  = (float*)d_out;
    unsigned long long* slots = (unsigned long long*)d_ws;  // 256 × u64

    const int L = 5, B = 16, N = 4096, T = 96;
    const float2* pred4 = (const float2*)pred + (size_t)(L - 1) * B * N;  // layer L-1
    const float2* gt4   = (const float2*)gt   + (size_t)(L - 1) * B * T;

    iou_onepass_kernel<<<dim3(B * 16), dim3(256), 0, stream>>>(pred4, gt4, bs, out, slots);
}

// Round 5
// 13.466 us; speedup vs baseline: 3.9013x; 1.8225x over previous
//
#include <hip/hip_runtime.h>

#define EPS 1e-6f
#define NBLK 2048   // 16 b × 16 n-chunks × 8 t-chunks

__global__ __launch_bounds__(256) void iou_partial_kernel(
    const float2* __restrict__ pred4,  // layer-4 base, (B=16, N=4096) float2
    const float2* __restrict__ gt4,    // layer-4 base, (B=16, T=96) float2
    float* __restrict__ partial)       // [NBLK] in d_ws
{
    __shared__ float wave_part[4];

    const int tid = threadIdx.x;
    const int blk = blockIdx.x;
    const int b  = blk >> 7;          // 128 blocks per b
    const int nc = (blk >> 3) & 15;   // n chunk of 256
    const int tc = blk & 7;           // t chunk of 12

    const float2 p = pred4[b * 4096 + nc * 256 + tid];
    const float s = p.x, e = p.y;

    const int gbase = b * 96 + tc * 12;

    float acc = 0.0f;  // sum of log2(iou) over valid pairs
#pragma unroll
    for (int t = 0; t < 12; ++t) {
        // uniform address (blockIdx-derived + loop const) -> scalar K$ load, no LDS
        const float2 g = gt4[gbase + t];
        const float a  = g.x;
        const float bb = g.y;
        const bool c0 = (s < a) & (e > bb);
        const bool c1 = (s < a) & (e < bb) & (e > a);
        const bool c2 = (s > a) & (s < bb) & (e > bb);
        const float num = c0 ? (bb - a) : (c1 ? (e - a) : (bb - s));
        const float den = c0 ? (e - s)  : (c1 ? (bb - s) : (e - a));
        // conditions mutually exclusive; den > 0 whenever any holds.
        // iou < EPS (incl. no-overlap / pred-inside-gt) -> ref maps to 1.0 -> log 0.
        const bool valid = (c0 | c1 | c2) && (num >= EPS * den);
        const float contrib = __log2f(num) - __log2f(den);
        acc += valid ? contrib : 0.0f;   // cndmask: NaN from garbage logs never selected
    }

    // wave butterfly then LDS across the 4 waves
    for (int off = 32; off; off >>= 1)
        acc += __shfl_down(acc, off);
    if ((tid & 63) == 0) wave_part[tid >> 6] = acc;
    __syncthreads();
    if (tid == 0)
        partial[blk] = wave_part[0] + wave_part[1] + wave_part[2] + wave_part[3];
}

__global__ __launch_bounds__(64) void iou_final_kernel(
    const float4* __restrict__ partial4,   // NBLK floats = NBLK/4 float4
    const int* __restrict__ bs_ptr,
    float* __restrict__ out)
{
    const int tid = threadIdx.x;   // one wave

    float v = 0.0f;
#pragma unroll
    for (int i = 0; i < NBLK / 4 / 64; ++i) {
        const float4 q = partial4[i * 64 + tid];
        v += (q.x + q.y) + (q.z + q.w);
    }

    for (int off = 32; off; off >>= 1)
        v += __shfl_down(v, off);

    if (tid == 0) {
        // loss = -sum(ln(iou)) / batch = -ln2 * sum(log2(iou)) / batch
        out[0] = v * (-0.69314718055994531f / (float)bs_ptr[0]);
    }
}

extern "C" void kernel_launch(void* const* d_in, const int* in_sizes, int n_in,
                              void* d_out, int out_size, void* d_ws, size_t ws_size,
                              hipStream_t stream) {
    (void)in_sizes; (void)n_in; (void)ws_size; (void)out_size;

    const float* pred = (const float*)d_in[0];   // (L,B,N,2) f32
    const float* gt   = (const float*)d_in[1];   // (L,B,T,2) f32
    const int*   bs   = (const int*)d_in[2];     // scalar
    float*       out  = (float*)d_out;
    float*       partial = (float*)d_ws;         // NBLK floats

    const int L = 5, B = 16, N = 4096, T = 96;
    const float2* pred4 = (const float2*)pred + (size_t)(L - 1) * B * N;  // layer L-1
    const float2* gt4   = (const float2*)gt   + (size_t)(L - 1) * B * T;

    iou_partial_kernel<<<dim3(NBLK), dim3(256), 0, stream>>>(pred4, gt4, partial);
    iou_final_kernel<<<dim3(1), dim3(64), 0, stream>>>((const float4*)partial, bs, out);
}

// Round 6
// 12.974 us; speedup vs baseline: 4.0492x; 1.0379x over previous
//
#include <hip/hip_runtime.h>

#define EPS 1e-6f
#define NBLK 2048   // 16 b × 32 n-chunks(128) ... = 16b × 32nc × 4tc, 64-thread wave-blocks

__global__ __launch_bounds__(64) void iou_partial_kernel(
    const float2* __restrict__ pred4,  // layer-4 base, (B=16, N=4096) float2
    const float2* __restrict__ gt4,    // layer-4 base, (B=16, T=96) float2
    float* __restrict__ partial)       // [NBLK] in d_ws
{
    const int tid = threadIdx.x;      // one wave, no LDS, no syncthreads
    const int blk = blockIdx.x;
    const int b  = blk >> 7;          // 128 blocks per b
    const int nc = (blk >> 2) & 31;   // n chunk of 128... (32 chunks × 128 preds? no: 64)
    // 4096 preds / 64 threads = 64 n-chunks; with 32 nc we take 2 preds per thread?
    // Simpler: 16b × 64nc × 2tc = 2048 blocks, 48 gt-iters.
    const int nc64 = (blk >> 1) & 63; // n chunk of 64
    const int tc   = blk & 1;         // t chunk of 48
    (void)nc;

    const float2 p = pred4[b * 4096 + nc64 * 64 + tid];
    const float s = p.x, e = p.y;

    const int gbase = b * 96 + tc * 48;

    float acc = 0.0f;  // sum of log2(iou) over valid pairs
#pragma unroll
    for (int t = 0; t < 48; ++t) {
        // uniform address (blockIdx-derived + loop const) -> scalar K$ load
        const float2 g = gt4[gbase + t];
        const float a  = g.x;
        const float bb = g.y;
        // validity: exact strict conditions of the reference (mutually exclusive)
        const bool c0 = (s < a) & (e > bb);
        const bool c1 = (s < a) & (e < bb) & (e > a);
        const bool c2 = (s > a) & (s < bb) & (e > bb);
        // on any valid case, num/den equal intersection/union:
        const float num = fminf(e, bb) - fmaxf(s, a);
        const float den = fmaxf(e, bb) - fminf(s, a);
        // iou < EPS (incl. no-overlap / pred-inside-gt) -> ref maps to 1.0 -> log 0.
        const bool valid = (c0 | c1 | c2) && (num >= EPS * den);
        const float contrib = __log2f(num) - __log2f(den);
        acc += valid ? contrib : 0.0f;   // cndmask: NaN from invalid logs never selected
    }

    // wave butterfly reduce, store straight from lane 0
    for (int off = 32; off; off >>= 1)
        acc += __shfl_down(acc, off);
    if (tid == 0)
        partial[blk] = acc;
}

__global__ __launch_bounds__(64) void iou_final_kernel(
    const float4* __restrict__ partial4,   // NBLK floats = NBLK/4 float4
    const int* __restrict__ bs_ptr,
    float* __restrict__ out)
{
    const int tid = threadIdx.x;   // one wave

    float v = 0.0f;
#pragma unroll
    for (int i = 0; i < NBLK / 4 / 64; ++i) {
        const float4 q = partial4[i * 64 + tid];
        v += (q.x + q.y) + (q.z + q.w);
    }

    for (int off = 32; off; off >>= 1)
        v += __shfl_down(v, off);

    if (tid == 0) {
        // loss = -sum(ln(iou)) / batch = -ln2 * sum(log2(iou)) / batch
        out[0] = v * (-0.69314718055994531f / (float)bs_ptr[0]);
    }
}

extern "C" void kernel_launch(void* const* d_in, const int* in_sizes, int n_in,
                              void* d_out, int out_size, void* d_ws, size_t ws_size,
                              hipStream_t stream) {
    (void)in_sizes; (void)n_in; (void)ws_size; (void)out_size;

    const float* pred = (const float*)d_in[0];   // (L,B,N,2) f32
    const float* gt   = (const float*)d_in[1];   // (L,B,T,2) f32
    const int*   bs   = (const int*)d_in[2];     // scalar
    float*       out  = (float*)d_out;
    float*       partial = (float*)d_ws;         // NBLK floats

    const int L = 5, B = 16, N = 4096, T = 96;
    const float2* pred4 = (const float2*)pred + (size_t)(L - 1) * B * N;  // layer L-1
    const float2* gt4   = (const float2*)gt   + (size_t)(L - 1) * B * T;

    iou_partial_kernel<<<dim3(NBLK), dim3(64), 0, stream>>>(pred4, gt4, partial);
    iou_final_kernel<<<dim3(1), dim3(64), 0, stream>>>((const float4*)partial, bs, out);
}